// Round 14
// baseline (233.082 us; speedup 1.0000x reference)
//
#include <hip/hip_runtime.h>
#include <math.h>

__device__ __forceinline__ float siluf_(float x) {
    return x / (1.f + __expf(-x));
}

// Direction permutation (involution): xs[k][d][l] = x0[d][sperm(k,l)]
__device__ __forceinline__ int sperm(int k, int l) {
    int t = (k & 1) ? (((l & 7) << 3) | (l >> 3)) : l;
    return (k & 2) ? (63 - t) : t;
}

// bf16 pack/unpack (RNE)
__device__ __forceinline__ unsigned int f2bf(float f) {
    unsigned int u = __float_as_uint(f);
    return (u + 0x7FFFu + ((u >> 16) & 1u)) >> 16;
}
__device__ __forceinline__ float bf2f(unsigned int h) {
    return __uint_as_float(h << 16);
}
__device__ __forceinline__ unsigned int packbf(float lo, float hi) {
    return f2bf(lo) | (f2bf(hi) << 16);
}
__device__ __forceinline__ float bflo(unsigned int u) { return __uint_as_float(u << 16); }
__device__ __forceinline__ float bfhi(unsigned int u) { return __uint_as_float(u & 0xFFFF0000u); }

// ---------------------------------------------------------------- k1a: stats
__global__ void k1a_stats(const float* __restrict__ x, float* __restrict__ stats) {
    int bc = blockIdx.x;                 // b*96 + c
    const float* xp = x + (size_t)bc * 4096;
    float s = 0.f, sq = 0.f;
    for (int i = threadIdx.x; i < 4096; i += 256) {
        float v = xp[i]; s += v; sq += v * v;
    }
    __shared__ float rs[256], rq[256];
    rs[threadIdx.x] = s; rq[threadIdx.x] = sq;
    __syncthreads();
    for (int off = 128; off > 0; off >>= 1) {
        if (threadIdx.x < off) {
            rs[threadIdx.x] += rs[threadIdx.x + off];
            rq[threadIdx.x] += rq[threadIdx.x + off];
        }
        __syncthreads();
    }
    if (threadIdx.x == 0) {
        float m = rs[0] * (1.f / 4096.f);
        float v = rq[0] * (1.f / 4096.f) - m * m;
        stats[bc] = m;
        stats[384 + bc] = rsqrtf(v + 1e-5f);
    }
}

// ---- kAB: spatial-norm+SiLU + LN(96) + in_proj (48 conv + 48 z cols) +
// depthwise conv from LDS. block = (chunk, q in {0..3}); grid 1024.
__global__ __launch_bounds__(256) void kAB(
        const float* __restrict__ x, const float* __restrict__ stats,
        const float* __restrict__ gamma, const float* __restrict__ beta,
        const float* __restrict__ ln1_g, const float* __restrict__ ln1_b,
        const float* __restrict__ Win,       // (96,384)
        const float* __restrict__ conv_w, const float* __restrict__ conv_b,
        float* __restrict__ x0T_all,         // [chunk][64][192]
        unsigned int* __restrict__ zg_b) {   // [chunk][96][64] packed bf16x2
    int blk = blockIdx.x;
    int xcd = blk & 7, j = blk >> 3;         // j: 0..127
    int chunk = xcd * 32 + (j >> 2), q = j & 3;
    int b = chunk >> 6, chh = (chunk >> 3) & 7, chw = chunk & 7;
    __shared__ float hs[64 * 97];
    __shared__ float xc[48 * 65];
    int t = threadIdx.x;
    // ph1: load x-chunk, spatial norm + SiLU -> hs[pos][c] (redundant per q)
    for (int i = t; i < 6144; i += 256) {
        int c = i >> 6, pos = i & 63;
        int bc = b * 96 + c;
        int hh = chh * 8 + (pos >> 3), ww = chw * 8 + (pos & 7);
        float v = x[(((size_t)bc) * 64 + hh) * 64 + ww];
        float xn = (v - stats[bc]) * stats[384 + bc] * gamma[c] + beta[c];
        hs[pos * 97 + c] = siluf_(xn);
    }
    __syncthreads();
    {   // ph2: LN over 96, 4 lanes per position, in place
        int p = t >> 2, o = t & 3;
        float s = 0.f, sq = 0.f;
        #pragma unroll
        for (int jj = 0; jj < 24; jj++) { float v = hs[p * 97 + o + 4 * jj]; s += v; sq += v * v; }
        s += __shfl_xor(s, 1); sq += __shfl_xor(sq, 1);
        s += __shfl_xor(s, 2); sq += __shfl_xor(sq, 2);
        float m = s * (1.f / 96.f);
        float rinv = rsqrtf(sq * (1.f / 96.f) - m * m + 1e-5f);
        #pragma unroll
        for (int jj = 0; jj < 24; jj++) {
            int c = o + 4 * jj;
            hs[p * 97 + c] = (hs[p * 97 + c] - m) * rinv * ln1_g[c] + ln1_b[c];
        }
    }
    __syncthreads();
    // ph3: GEMV 96 -> 24 cols/wave (12 conv + 12 z), wave-uniform weights
    {
        int p = t & 63;
        int wv = __builtin_amdgcn_readfirstlane(t >> 6);   // 0..3
        int jc = q * 48 + wv * 12;           // conv col base in [0,192)
        int jz = 192 + jc;                   // z col base
        float acc[24];
        #pragma unroll
        for (int i = 0; i < 24; i++) acc[i] = 0.f;
        for (int c = 0; c < 96; c++) {
            float u = hs[p * 97 + c];
            const float* w = Win + c * 384;
            #pragma unroll
            for (int i = 0; i < 12; i++) acc[i] = fmaf(u, w[jc + i], acc[i]);
            #pragma unroll
            for (int i = 0; i < 12; i++) acc[12 + i] = fmaf(u, w[jz + i], acc[12 + i]);
        }
        #pragma unroll
        for (int i = 0; i < 12; i++) xc[(wv * 12 + i) * 65 + p] = acc[i];
        int i2base = q * 24 + wv * 6;
        unsigned int* o_ = zg_b + (size_t)chunk * 6144 + i2base * 64 + p;
        #pragma unroll
        for (int m2 = 0; m2 < 6; m2++)
            o_[m2 * 64] = packbf(acc[12 + 2 * m2], acc[12 + 2 * m2 + 1]);
    }
    __syncthreads();
    // ph4: depthwise 3x3 + bias + SiLU from LDS -> x0T[l][192] (this q's 48 ch)
    {
        float* x0o = x0T_all + (size_t)chunk * 12288 + q * 48;
        for (int s = 0; s < 12; s++) {
            int idx = s * 256 + t;               // < 3072
            int l = idx / 48, dl = idx - l * 48;
            int d = q * 48 + dl;
            int r = l >> 3, cc = l & 7;
            float acc = conv_b[d];
            #pragma unroll
            for (int dh = 0; dh < 3; dh++) {
                int rr = r + dh - 1;
                if (rr < 0 || rr > 7) continue;
                #pragma unroll
                for (int dw = 0; dw < 3; dw++) {
                    int cw = cc + dw - 1;
                    if (cw < 0 || cw > 7) continue;
                    acc = fmaf(xc[dl * 65 + rr * 8 + cw], conv_w[d * 9 + dh * 3 + dw], acc);
                }
            }
            x0o[l * 192 + dl] = siluf_(acc);
        }
    }
}

// ---- kD: block = (chunk, k), 384 threads = 2 per channel (h = t&1, 8 states
// each). proj -> pT (f32) -> repacked pTp (dts f32 + B/C bf16): scan reads
// 4 ds ops/step instead of 6 (the CU-shared LDS pipe was the limiter).
__global__ __launch_bounds__(384, 6) void kD(
        const float* __restrict__ x0T_all, const float* __restrict__ xpw, // (4,38,192)
        const float* __restrict__ dtw, const float* __restrict__ dtb,
        const float* __restrict__ A_logs, const float* __restrict__ Ds,
        unsigned int* __restrict__ yk01,     // [2][chunk][64][96] bf16x2
        unsigned int* __restrict__ yk23) {   // [2][chunk][64][96] bf16x2
    int blk = blockIdx.x;
    int xcd = blk & 7, j = blk >> 3;         // j: 0..127
    int chunk = xcd * 32 + (j >> 2);
    int k = j & 3;
    __shared__ float pT[64 * 40];            // f32: 0-5 dts, 8-23 B, 24-39 C
    __shared__ unsigned int pTp[64 * 24];    // 0-5 dts(f32 bits), 8-15 B/C h0, 16-23 B/C h1
    int t = threadIdx.x;
    const float* xbase = x0T_all + (size_t)chunk * 12288;

    // proj: P[c][l] = sum_dd xpw[k][c][dd] * x0T[l][dd]; 6 waves x 7 cols
    {
        int l = t & 63;
        int wv6 = __builtin_amdgcn_readfirstlane(t >> 6);  // 0..5
        int cbase = wv6 * 7;
        float acc[7];
        #pragma unroll
        for (int i = 0; i < 7; i++) acc[i] = 0.f;
        const float* xl = xbase + l * 192;
        const float* wb = xpw + (size_t)k * 38 * 192;
        for (int dd = 0; dd < 192; dd += 4) {
            float4 u4 = *(const float4*)(xl + dd);         // per-lane, coalesced
            #pragma unroll
            for (int ci = 0; ci < 7; ci++) {
                int c = cbase + ci;
                if (c < 38) {
                    float4 w4 = *(const float4*)(wb + c * 192 + dd);  // s_load
                    acc[ci] = fmaf(u4.x, w4.x, acc[ci]);
                    acc[ci] = fmaf(u4.y, w4.y, acc[ci]);
                    acc[ci] = fmaf(u4.z, w4.z, acc[ci]);
                    acc[ci] = fmaf(u4.w, w4.w, acc[ci]);
                }
            }
        }
        #pragma unroll
        for (int ci = 0; ci < 7; ci++) {
            int c = cbase + ci;
            if (c < 38) {
                int slot = c + (c >= 6 ? 2 : 0);
                pT[l * 40 + slot] = acc[ci];
            }
        }
    }
    __syncthreads();
    // repack: pTp row = [dts f32 x6][pad x2][B_h0 4u32][C_h0 4u32][B_h1][C_h1]
    for (int i = t; i < 1536; i += 384) {
        int l = i / 24, s = i - l * 24;
        unsigned int v = 0;
        if (s < 6) v = __float_as_uint(pT[l * 40 + s]);
        else if (s >= 8) {
            int qq = s - 8;              // 0..15
            int half = qq >> 3;
            int w = qq & 7;
            int isC = w >> 2;
            int pr = w & 3;
            int n = half * 8 + pr * 2;
            int slot = (isC ? 24 : 8) + n;
            v = packbf(pT[l * 40 + slot], pT[l * 40 + slot + 1]);
        }
        pTp[i] = v;
    }
    __syncthreads();

    // scan: thread (d = t>>1, h = t&1) owns states [8h, 8h+8) of channel d
    {
        int d = t >> 1, h = t & 1;
        int gd = k * 192 + d;
        float w6[6];
        #pragma unroll
        for (int r = 0; r < 6; r++) w6[r] = dtw[gd * 6 + r];
        float bias = dtb[gd];
        float Dd_eff = h ? 0.f : Ds[gd];     // D-term counted once per channel
        float a0 = -__expf(A_logs[gd * 16]);
        float a8[8];
        #pragma unroll
        for (int n = 0; n < 8; n++) a8[n] = -__expf(A_logs[gd * 16 + 8 * h + n]);
        bool pw = true;
        #pragma unroll
        for (int n = 0; n < 8; n++) {
            float tgt = (float)(8 * h + n + 1) * a0;
            pw = pw && (fabsf(a8[n] - tgt) <= 1e-4f * fabsf(tgt) + 1e-6f);
        }
        bool a0m1 = (a0 == -1.0f);
        float c0 = a0 * (float)(8 * h + 1);
        float hst[8];
        #pragma unroll
        for (int n = 0; n < 8; n++) hst[n] = 0.f;
        unsigned int* yb = (k < 2 ? yk01 : yk23) + (size_t)(k & 1) * 1572864
                           + (size_t)chunk * 6144;
        int hb = 8 * h;                      // f32-layout offset (fallback paths)

        if (__all(pw && a0m1)) {
            // sigmoid fast path, 2-step pairs, packed bf16 B/C
            for (int g8 = 0; g8 < 8; ++g8) {
                float u8[8];
                #pragma unroll
                for (int i = 0; i < 8; i++)
                    u8[i] = xbase[sperm(k, g8 * 8 + i) * 192 + d];   // batched issue
                #pragma unroll
                for (int i = 0; i < 8; i += 2) {
                    int sl0 = sperm(k, g8 * 8 + i);
                    int sl1 = sperm(k, g8 * 8 + i + 1);
                    const unsigned int* row0 = pTp + sl0 * 24;
                    const unsigned int* row1 = pTp + sl1 * 24;
                    float4 rA0 = *(const float4*)(row0);
                    float2 rB0 = *(const float2*)((const float*)row0 + 4);
                    uint4 Bp0 = *(const uint4*)(row0 + 8 + h * 8);
                    uint4 Cp0 = *(const uint4*)(row0 + 12 + h * 8);
                    float4 rA1 = *(const float4*)(row1);
                    float2 rB1 = *(const float2*)((const float*)row1 + 4);
                    uint4 Bp1 = *(const uint4*)(row1 + 8 + h * 8);
                    uint4 Cp1 = *(const uint4*)(row1 + 12 + h * 8);
                    float dp0 = bias, dp1 = bias;
                    dp0 = fmaf(rA0.x, w6[0], dp0); dp1 = fmaf(rA1.x, w6[0], dp1);
                    dp0 = fmaf(rA0.y, w6[1], dp0); dp1 = fmaf(rA1.y, w6[1], dp1);
                    dp0 = fmaf(rA0.z, w6[2], dp0); dp1 = fmaf(rA1.z, w6[2], dp1);
                    dp0 = fmaf(rA0.w, w6[3], dp0); dp1 = fmaf(rA1.w, w6[3], dp1);
                    dp0 = fmaf(rB0.x, w6[4], dp0); dp1 = fmaf(rB1.x, w6[4], dp1);
                    dp0 = fmaf(rB0.y, w6[5], dp0); dp1 = fmaf(rB1.y, w6[5], dp1);
                    float ex0 = __expf(dp0), ex1 = __expf(dp1);
                    float delta0 = (dp0 > 20.f) ? dp0 : __logf(1.f + ex0);
                    float delta1 = (dp1 > 20.f) ? dp1 : __logf(1.f + ex1);
                    float e10 = __builtin_amdgcn_rcpf(1.f + ex0);  // exp(-delta0)
                    float e11 = __builtin_amdgcn_rcpf(1.f + ex1);
                    float du0 = delta0 * u8[i];
                    float du1 = delta1 * u8[i + 1];
                    float e20 = e10 * e10, e40 = e20 * e20;
                    float eb0 = h ? (e40 * e40 * e10) : e10;
                    float p0 = eb0,       p1 = eb0 * e10, p2 = eb0 * e20, p3 = p1 * e20;
                    float p4 = eb0 * e40, p5 = p1 * e40,  p6 = p2 * e40,  p7 = p3 * e40;
                    float e21 = e11 * e11, e41 = e21 * e21;
                    float eb1 = h ? (e41 * e41 * e11) : e11;
                    float q0 = eb1,       q1 = eb1 * e11, q2 = eb1 * e21, q3 = q1 * e21;
                    float q4 = eb1 * e41, q5 = q1 * e41,  q6 = q2 * e41,  q7 = q3 * e41;
                    float ya, yb_;
                    hst[0] = fmaf(hst[0], p0, du0 * bflo(Bp0.x)); ya  = hst[0] * bflo(Cp0.x);
                    hst[1] = fmaf(hst[1], p1, du0 * bfhi(Bp0.x)); yb_ = hst[1] * bfhi(Cp0.x);
                    hst[2] = fmaf(hst[2], p2, du0 * bflo(Bp0.y)); ya  = fmaf(hst[2], bflo(Cp0.y), ya);
                    hst[3] = fmaf(hst[3], p3, du0 * bfhi(Bp0.y)); yb_ = fmaf(hst[3], bfhi(Cp0.y), yb_);
                    hst[4] = fmaf(hst[4], p4, du0 * bflo(Bp0.z)); ya  = fmaf(hst[4], bflo(Cp0.z), ya);
                    hst[5] = fmaf(hst[5], p5, du0 * bfhi(Bp0.z)); yb_ = fmaf(hst[5], bfhi(Cp0.z), yb_);
                    hst[6] = fmaf(hst[6], p6, du0 * bflo(Bp0.w)); ya  = fmaf(hst[6], bflo(Cp0.w), ya);
                    hst[7] = fmaf(hst[7], p7, du0 * bfhi(Bp0.w)); yb_ = fmaf(hst[7], bfhi(Cp0.w), yb_);
                    float yp0 = fmaf(Dd_eff, u8[i], ya + yb_);
                    float yf0 = yp0 + __shfl_xor(yp0, 1);
                    float yo0 = __shfl_xor(yf0, 2);
                    if ((t & 3) == 0) yb[sl0 * 96 + (d >> 1)] = packbf(yf0, yo0);
                    hst[0] = fmaf(hst[0], q0, du1 * bflo(Bp1.x)); ya  = hst[0] * bflo(Cp1.x);
                    hst[1] = fmaf(hst[1], q1, du1 * bfhi(Bp1.x)); yb_ = hst[1] * bfhi(Cp1.x);
                    hst[2] = fmaf(hst[2], q2, du1 * bflo(Bp1.y)); ya  = fmaf(hst[2], bflo(Cp1.y), ya);
                    hst[3] = fmaf(hst[3], q3, du1 * bfhi(Bp1.y)); yb_ = fmaf(hst[3], bfhi(Cp1.y), yb_);
                    hst[4] = fmaf(hst[4], q4, du1 * bflo(Bp1.z)); ya  = fmaf(hst[4], bflo(Cp1.z), ya);
                    hst[5] = fmaf(hst[5], q5, du1 * bfhi(Bp1.z)); yb_ = fmaf(hst[5], bfhi(Cp1.z), yb_);
                    hst[6] = fmaf(hst[6], q6, du1 * bflo(Bp1.w)); ya  = fmaf(hst[6], bflo(Cp1.w), ya);
                    hst[7] = fmaf(hst[7], q7, du1 * bfhi(Bp1.w)); yb_ = fmaf(hst[7], bfhi(Cp1.w), yb_);
                    float yp1 = fmaf(Dd_eff, u8[i + 1], ya + yb_);
                    float yf1 = yp1 + __shfl_xor(yp1, 1);
                    float yo1 = __shfl_xor(yf1, 2);
                    if ((t & 3) == 0) yb[sl1 * 96 + (d >> 1)] = packbf(yf1, yo1);
                }
            }
        } else if (__all(pw)) {
            for (int g8 = 0; g8 < 8; ++g8) {
                float u8[8];
                #pragma unroll
                for (int i = 0; i < 8; i++)
                    u8[i] = xbase[sperm(k, g8 * 8 + i) * 192 + d];
                #pragma unroll
                for (int i = 0; i < 8; i++) {
                    int sl = sperm(k, g8 * 8 + i);
                    const float* row = pT + sl * 40;
                    float4 rA = *(const float4*)(row);
                    float2 rB = *(const float2*)(row + 4);
                    float dp = bias;
                    dp = fmaf(rA.x, w6[0], dp); dp = fmaf(rA.y, w6[1], dp);
                    dp = fmaf(rA.z, w6[2], dp); dp = fmaf(rA.w, w6[3], dp);
                    dp = fmaf(rB.x, w6[4], dp); dp = fmaf(rB.y, w6[5], dp);
                    float delta = (dp > 20.f) ? dp : __logf(1.f + __expf(dp));
                    float du = delta * u8[i];
                    float e1 = __expf(delta * a0);
                    float eb = __expf(delta * c0);
                    float e2 = e1 * e1, e4 = e2 * e2;
                    float p0 = eb,      p1 = eb * e1, p2 = eb * e2, p3 = p1 * e2;
                    float p4 = p0 * e4, p5 = p1 * e4, p6 = p2 * e4, p7 = p3 * e4;
                    float4 bq0 = *(const float4*)(row + 8 + hb);
                    float4 bq1 = *(const float4*)(row + 12 + hb);
                    float4 cq0 = *(const float4*)(row + 24 + hb);
                    float4 cq1 = *(const float4*)(row + 28 + hb);
                    float y0, y1;
                    hst[0] = fmaf(hst[0], p0, du * bq0.x); y0 = hst[0] * cq0.x;
                    hst[1] = fmaf(hst[1], p1, du * bq0.y); y1 = hst[1] * cq0.y;
                    hst[2] = fmaf(hst[2], p2, du * bq0.z); y0 = fmaf(hst[2], cq0.z, y0);
                    hst[3] = fmaf(hst[3], p3, du * bq0.w); y1 = fmaf(hst[3], cq0.w, y1);
                    hst[4] = fmaf(hst[4], p4, du * bq1.x); y0 = fmaf(hst[4], cq1.x, y0);
                    hst[5] = fmaf(hst[5], p5, du * bq1.y); y1 = fmaf(hst[5], cq1.y, y1);
                    hst[6] = fmaf(hst[6], p6, du * bq1.z); y0 = fmaf(hst[6], cq1.z, y0);
                    hst[7] = fmaf(hst[7], p7, du * bq1.w); y1 = fmaf(hst[7], cq1.w, y1);
                    float yp = fmaf(Dd_eff, u8[i], y0 + y1);
                    float yfull = yp + __shfl_xor(yp, 1);
                    float yo2 = __shfl_xor(yfull, 2);
                    if ((t & 3) == 0) yb[sl * 96 + (d >> 1)] = packbf(yfull, yo2);
                }
            }
        } else {
            for (int l = 0; l < 64; l++) {
                int sl = sperm(k, l);
                float u = xbase[sl * 192 + d];
                const float* row = pT + sl * 40;
                float dp = bias;
                #pragma unroll
                for (int r = 0; r < 6; r++) dp = fmaf(row[r], w6[r], dp);
                float delta = (dp > 20.f) ? dp : __logf(1.f + __expf(dp));
                float du = delta * u;
                float yp = 0.f;
                #pragma unroll
                for (int n = 0; n < 8; n++) {
                    float e = __expf(delta * a8[n]);
                    hst[n] = fmaf(hst[n], e, du * row[8 + hb + n]);
                    yp = fmaf(hst[n], row[24 + hb + n], yp);
                }
                yp = fmaf(Dd_eff, u, yp);
                float yfull = yp + __shfl_xor(yp, 1);
                float yo2 = __shfl_xor(yfull, 2);
                if ((t & 3) == 0) yb[sl * 96 + (d >> 1)] = packbf(yfull, yo2);
            }
        }
    }
}

// ---- kEF: y = sum of 4 bf16 partials; LN(192)+silu(z) gate -> gs (32 pos);
// out_proj GEMV (48 cols) + residual recompute + final blend.
// block = (chunk, ph in {0,1}, ch in {0,1}); grid 1024.
__global__ __launch_bounds__(256) void kEF(
        const unsigned int* __restrict__ yk01, const unsigned int* __restrict__ yk23,
        const unsigned int* __restrict__ zg_b,
        const float* __restrict__ og, const float* __restrict__ ob,
        const float* __restrict__ Wout,        // (192,96)
        const float* __restrict__ x, const float* __restrict__ stats,
        const float* __restrict__ gamma, const float* __restrict__ beta,
        const float* __restrict__ alpha, float* __restrict__ out) {
    int blk = blockIdx.x;
    int xcd = blk & 7, j = blk >> 3;         // j: 0..127
    int chunk = xcd * 32 + (j >> 2);
    int ph = (j >> 1) & 1, ch = j & 1;
    int b = chunk >> 6, chh = (chunk >> 3) & 7, chw = chunk & 7;
    __shared__ float gs[32 * 193];
    int t = threadIdx.x;
    // gate for positions [ph*32, +32): 8 lanes per position
    {
        int pl = t >> 3, o = t & 7;
        int p = ph * 32 + pl;
        int par = o & 1;
        size_t rb = (size_t)chunk * 6144 + p * 96;
        const unsigned int* r0 = yk01 + rb;
        const unsigned int* r1 = yk01 + 1572864 + rb;
        const unsigned int* r2 = yk23 + rb;
        const unsigned int* r3 = yk23 + 1572864 + rb;
        float ys[24];
        float s = 0.f, sq = 0.f;
        #pragma unroll
        for (int jj = 0; jj < 24; jj++) {
            int i = o + 8 * jj;
            int wi = i >> 1;
            int sh = par ? 16 : 0;
            float v = bf2f((r0[wi] >> sh) & 0xFFFFu) + bf2f((r1[wi] >> sh) & 0xFFFFu)
                    + bf2f((r2[wi] >> sh) & 0xFFFFu) + bf2f((r3[wi] >> sh) & 0xFFFFu);
            ys[jj] = v; s += v; sq += v * v;
        }
        s += __shfl_xor(s, 1); sq += __shfl_xor(sq, 1);
        s += __shfl_xor(s, 2); sq += __shfl_xor(sq, 2);
        s += __shfl_xor(s, 4); sq += __shfl_xor(sq, 4);
        float m = s * (1.f / 192.f);
        float rinv = rsqrtf(sq * (1.f / 192.f) - m * m + 1e-5f);
        const unsigned int* z = zg_b + (size_t)chunk * 6144;
        #pragma unroll
        for (int jj = 0; jj < 24; jj++) {
            int i = o + 8 * jj;
            float ln = (ys[jj] - m) * rinv * og[i] + ob[i];
            unsigned int zw = z[(i >> 1) * 64 + p];
            float zv = bf2f(par ? (zw >> 16) : (zw & 0xFFFFu));
            gs[pl * 193 + i] = ln * siluf_(zv);
        }
    }
    __syncthreads();
    // out_proj GEMV: 32 pos x 48 cols; u from LDS (2 lanes/bank, conflict-free)
    {
        int pl = t & 31;
        int g32 = t >> 5;                    // 0..7
        int cbase = ch * 48 + g32 * 6;
        float acc[6];
        #pragma unroll
        for (int i = 0; i < 6; i++) acc[i] = 0.f;
        for (int dd = 0; dd < 192; dd++) {
            float u = gs[pl * 193 + dd];
            const float* w = Wout + dd * 96 + cbase;
            #pragma unroll
            for (int i = 0; i < 6; i++) acc[i] = fmaf(u, w[i], acc[i]);
        }
        float al = alpha[0];
        int p = ph * 32 + pl;
        int hh = chh * 8 + (p >> 3), ww = chw * 8 + (p & 7);
        #pragma unroll
        for (int i = 0; i < 6; i++) {
            int c = cbase + i;
            int bc = b * 96 + c;
            size_t gi = (((size_t)bc) * 64 + hh) * 64 + ww;
            float xv = x[gi];
            float xn = (xv - stats[bc]) * stats[384 + bc] * gamma[c] + beta[c];
            out[gi] = xv + al * (siluf_(xn) + acc[i]);
        }
    }
}

extern "C" void kernel_launch(void* const* d_in, const int* in_sizes, int n_in,
                              void* d_out, int out_size, void* d_ws, size_t ws_size,
                              hipStream_t stream) {
    const float* x        = (const float*)d_in[0];
    const float* gamma    = (const float*)d_in[1];
    const float* beta     = (const float*)d_in[2];
    const float* alpha    = (const float*)d_in[3];
    const float* ln1_g    = (const float*)d_in[4];
    const float* ln1_b    = (const float*)d_in[5];
    const float* in_proj  = (const float*)d_in[6];
    const float* conv_w   = (const float*)d_in[7];
    const float* conv_b   = (const float*)d_in[8];
    const float* x_proj   = (const float*)d_in[9];
    const float* dt_w     = (const float*)d_in[10];
    const float* dt_b     = (const float*)d_in[11];
    const float* A_logs   = (const float*)d_in[12];
    const float* Ds       = (const float*)d_in[13];
    const float* onorm_g  = (const float*)d_in[14];
    const float* onorm_b  = (const float*)d_in[15];
    const float* out_proj = (const float*)d_in[16];
    float* out = (float*)d_out;

    float* ws    = (float*)d_ws;
    float* stats = ws;                            // 768 f
    float* x0T   = ws + 768;                      // 3,145,728 f
    unsigned int* zg_b = (unsigned int*)(x0T + 3145728);   // 1,572,864 u32
    unsigned int* yk01 = zg_b + 1572864;          // 3,145,728 u32
    unsigned int* yk23 = yk01 + 3145728;          // 3,145,728 u32 (total 44.04 MB, proven)

    hipLaunchKernelGGL(k1a_stats, dim3(384), dim3(256), 0, stream, x, stats);
    hipLaunchKernelGGL(kAB, dim3(1024), dim3(256), 0, stream,
                       x, stats, gamma, beta, ln1_g, ln1_b, in_proj,
                       conv_w, conv_b, x0T, zg_b);
    hipLaunchKernelGGL(kD, dim3(1024), dim3(384), 0, stream,
                       x0T, x_proj, dt_w, dt_b, A_logs, Ds, yk01, yk23);
    hipLaunchKernelGGL(kEF, dim3(1024), dim3(256), 0, stream,
                       yk01, yk23, zg_b, onorm_g, onorm_b, out_proj,
                       x, stats, gamma, beta, alpha, out);
}

// Round 15
// 181.483 us; speedup vs baseline: 1.2843x; 1.2843x over previous
//
#include <hip/hip_runtime.h>
#include <math.h>

__device__ __forceinline__ float siluf_(float x) {
    return x / (1.f + __expf(-x));
}

// Direction permutation (involution): xs[k][d][l] = x0[d][sperm(k,l)]
__device__ __forceinline__ int sperm(int k, int l) {
    int t = (k & 1) ? (((l & 7) << 3) | (l >> 3)) : l;
    return (k & 2) ? (63 - t) : t;
}

// bf16 pack/unpack (RNE)
__device__ __forceinline__ unsigned int f2bf(float f) {
    unsigned int u = __float_as_uint(f);
    return (u + 0x7FFFu + ((u >> 16) & 1u)) >> 16;
}
__device__ __forceinline__ float bf2f(unsigned int h) {
    return __uint_as_float(h << 16);
}
__device__ __forceinline__ unsigned int packbf(float lo, float hi) {
    return f2bf(lo) | (f2bf(hi) << 16);
}

// ---------------------------------------------------------------- k1a: stats
__global__ void k1a_stats(const float* __restrict__ x, float* __restrict__ stats) {
    int bc = blockIdx.x;                 // b*96 + c
    const float* xp = x + (size_t)bc * 4096;
    float s = 0.f, sq = 0.f;
    for (int i = threadIdx.x; i < 4096; i += 256) {
        float v = xp[i]; s += v; sq += v * v;
    }
    __shared__ float rs[256], rq[256];
    rs[threadIdx.x] = s; rq[threadIdx.x] = sq;
    __syncthreads();
    for (int off = 128; off > 0; off >>= 1) {
        if (threadIdx.x < off) {
            rs[threadIdx.x] += rs[threadIdx.x + off];
            rq[threadIdx.x] += rq[threadIdx.x + off];
        }
        __syncthreads();
    }
    if (threadIdx.x == 0) {
        float m = rs[0] * (1.f / 4096.f);
        float v = rq[0] * (1.f / 4096.f) - m * m;
        stats[bc] = m;
        stats[384 + bc] = rsqrtf(v + 1e-5f);
    }
}

// ---- kAB: spatial-norm+SiLU + LN(96) + in_proj (96 conv + 96 z cols) +
// depthwise conv from LDS. block = (chunk, cg in {0,1}); grid 512 x 512 thr.
// 512 threads -> 8 waves -> 16 waves/CU at 2 blocks/CU (50 KB LDS).
__global__ __launch_bounds__(512, 4) void kAB(
        const float* __restrict__ x, const float* __restrict__ stats,
        const float* __restrict__ gamma, const float* __restrict__ beta,
        const float* __restrict__ ln1_g, const float* __restrict__ ln1_b,
        const float* __restrict__ Win,       // (96,384)
        const float* __restrict__ conv_w, const float* __restrict__ conv_b,
        float* __restrict__ x0T_all,         // [chunk][64][192]
        unsigned int* __restrict__ zg_b) {   // [chunk][96][64] packed bf16x2
    int blk = blockIdx.x;
    int xcd = blk & 7, j = blk >> 3;         // j: 0..63
    int chunk = xcd * 32 + (j >> 1), cg = j & 1;
    int b = chunk >> 6, chh = (chunk >> 3) & 7, chw = chunk & 7;
    __shared__ float hs[64 * 97];
    __shared__ float xc[96 * 65];
    int t = threadIdx.x;
    // ph1: load x-chunk, spatial norm + SiLU -> hs[pos][c]
    for (int i = t; i < 6144; i += 512) {
        int c = i >> 6, pos = i & 63;
        int bc = b * 96 + c;
        int hh = chh * 8 + (pos >> 3), ww = chw * 8 + (pos & 7);
        float v = x[(((size_t)bc) * 64 + hh) * 64 + ww];
        float xn = (v - stats[bc]) * stats[384 + bc] * gamma[c] + beta[c];
        hs[pos * 97 + c] = siluf_(xn);
    }
    __syncthreads();
    {   // ph2: LN over 96, 8 lanes per position, in place
        int p = t >> 3, o = t & 7;
        float s = 0.f, sq = 0.f;
        #pragma unroll
        for (int jj = 0; jj < 12; jj++) { float v = hs[p * 97 + o + 8 * jj]; s += v; sq += v * v; }
        s += __shfl_xor(s, 1); sq += __shfl_xor(sq, 1);
        s += __shfl_xor(s, 2); sq += __shfl_xor(sq, 2);
        s += __shfl_xor(s, 4); sq += __shfl_xor(sq, 4);
        float m = s * (1.f / 96.f);
        float rinv = rsqrtf(sq * (1.f / 96.f) - m * m + 1e-5f);
        #pragma unroll
        for (int jj = 0; jj < 12; jj++) {
            int c = o + 8 * jj;
            hs[p * 97 + c] = (hs[p * 97 + c] - m) * rinv * ln1_g[c] + ln1_b[c];
        }
    }
    __syncthreads();
    // ph3: GEMV 96 -> 24 cols/wave (12 conv + 12 z), wave-uniform weights
    {
        int p = t & 63;
        int wv = __builtin_amdgcn_readfirstlane(t >> 6);   // 0..7
        int jc = cg * 96 + wv * 12;          // conv col base in [0,192)
        int jz = 192 + jc;                   // z col base
        float acc[24];
        #pragma unroll
        for (int i = 0; i < 24; i++) acc[i] = 0.f;
        for (int c = 0; c < 96; c++) {
            float u = hs[p * 97 + c];
            const float* w = Win + c * 384;
            #pragma unroll
            for (int i = 0; i < 12; i++) acc[i] = fmaf(u, w[jc + i], acc[i]);
            #pragma unroll
            for (int i = 0; i < 12; i++) acc[12 + i] = fmaf(u, w[jz + i], acc[12 + i]);
        }
        #pragma unroll
        for (int i = 0; i < 12; i++) xc[(wv * 12 + i) * 65 + p] = acc[i];
        int i2base = cg * 48 + wv * 6;
        unsigned int* o_ = zg_b + (size_t)chunk * 6144 + i2base * 64 + p;
        #pragma unroll
        for (int m2 = 0; m2 < 6; m2++)
            o_[m2 * 64] = packbf(acc[12 + 2 * m2], acc[12 + 2 * m2 + 1]);
    }
    __syncthreads();
    // ph4: depthwise 3x3 + bias + SiLU from LDS -> x0T[l][192] (this cg's half)
    {
        float* x0o = x0T_all + (size_t)chunk * 12288 + cg * 96;
        for (int s = 0; s < 12; s++) {
            int idx = s * 512 + t;               // < 6144
            int l = idx / 96, dl = idx - l * 96;
            int d = cg * 96 + dl;
            int r = l >> 3, cc = l & 7;
            float acc = conv_b[d];
            #pragma unroll
            for (int dh = 0; dh < 3; dh++) {
                int rr = r + dh - 1;
                if (rr < 0 || rr > 7) continue;
                #pragma unroll
                for (int dw = 0; dw < 3; dw++) {
                    int cw = cc + dw - 1;
                    if (cw < 0 || cw > 7) continue;
                    acc = fmaf(xc[dl * 65 + rr * 8 + cw], conv_w[d * 9 + dh * 3 + dw], acc);
                }
            }
            x0o[l * 192 + dl] = siluf_(acc);
        }
    }
}

// ---- kD: block = (chunk, k), 384 threads = 2 per channel (h = t&1, 8 states
// each). proj -> pT in LDS; 2-step-paired scan with sigmoid fast path
// (a0 == -1 => exp(delta*a0) = 1/(1+exp(dp)), rcp instead of exp).
// [round-11 version, 112 us known — do not touch]
__global__ __launch_bounds__(384, 6) void kD(
        const float* __restrict__ x0T_all, const float* __restrict__ xpw, // (4,38,192)
        const float* __restrict__ dtw, const float* __restrict__ dtb,
        const float* __restrict__ A_logs, const float* __restrict__ Ds,
        unsigned int* __restrict__ yk01,     // [2][chunk][64][96] bf16x2
        unsigned int* __restrict__ yk23) {   // [2][chunk][64][96] bf16x2
    int blk = blockIdx.x;
    int xcd = blk & 7, j = blk >> 3;         // j: 0..127
    int chunk = xcd * 32 + (j >> 2);
    int k = j & 3;
    __shared__ float pT[64 * 40];            // [l][slot]: 0-5 dts, 8-23 B, 24-39 C
    int t = threadIdx.x;
    const float* xbase = x0T_all + (size_t)chunk * 12288;

    // proj: P[c][l] = sum_dd xpw[k][c][dd] * x0T[l][dd]; 6 waves x 7 cols
    {
        int l = t & 63;
        int wv6 = __builtin_amdgcn_readfirstlane(t >> 6);  // 0..5
        int cbase = wv6 * 7;
        float acc[7];
        #pragma unroll
        for (int i = 0; i < 7; i++) acc[i] = 0.f;
        const float* xl = xbase + l * 192;
        const float* wb = xpw + (size_t)k * 38 * 192;
        for (int dd = 0; dd < 192; dd += 4) {
            float4 u4 = *(const float4*)(xl + dd);         // per-lane, coalesced
            #pragma unroll
            for (int ci = 0; ci < 7; ci++) {
                int c = cbase + ci;
                if (c < 38) {
                    float4 w4 = *(const float4*)(wb + c * 192 + dd);  // s_load
                    acc[ci] = fmaf(u4.x, w4.x, acc[ci]);
                    acc[ci] = fmaf(u4.y, w4.y, acc[ci]);
                    acc[ci] = fmaf(u4.z, w4.z, acc[ci]);
                    acc[ci] = fmaf(u4.w, w4.w, acc[ci]);
                }
            }
        }
        #pragma unroll
        for (int ci = 0; ci < 7; ci++) {
            int c = cbase + ci;
            if (c < 38) {
                int slot = c + (c >= 6 ? 2 : 0);
                pT[l * 40 + slot] = acc[ci];
            }
        }
    }
    __syncthreads();

    // scan: thread (d = t>>1, h = t&1) owns states [8h, 8h+8) of channel d
    {
        int d = t >> 1, h = t & 1;
        int gd = k * 192 + d;
        float w6[6];
        #pragma unroll
        for (int r = 0; r < 6; r++) w6[r] = dtw[gd * 6 + r];
        float bias = dtb[gd];
        float Dd_eff = h ? 0.f : Ds[gd];     // D-term counted once per channel
        float a0 = -__expf(A_logs[gd * 16]);
        float a8[8];
        #pragma unroll
        for (int n = 0; n < 8; n++) a8[n] = -__expf(A_logs[gd * 16 + 8 * h + n]);
        bool pw = true;
        #pragma unroll
        for (int n = 0; n < 8; n++) {
            float tgt = (float)(8 * h + n + 1) * a0;
            pw = pw && (fabsf(a8[n] - tgt) <= 1e-4f * fabsf(tgt) + 1e-6f);
        }
        bool a0m1 = (a0 == -1.0f);
        float c0 = a0 * (float)(8 * h + 1);
        float hst[8];
        #pragma unroll
        for (int n = 0; n < 8; n++) hst[n] = 0.f;
        unsigned int* yb = (k < 2 ? yk01 : yk23) + (size_t)(k & 1) * 1572864
                           + (size_t)chunk * 6144;
        int hb = 8 * h;                      // float offset of this half's B/C

        if (__all(pw && a0m1)) {
            // sigmoid fast path, 2-step pairs
            for (int g8 = 0; g8 < 8; ++g8) {
                float u8[8];
                #pragma unroll
                for (int i = 0; i < 8; i++)
                    u8[i] = xbase[sperm(k, g8 * 8 + i) * 192 + d];   // batched issue
                #pragma unroll
                for (int i = 0; i < 8; i += 2) {
                    int sl0 = sperm(k, g8 * 8 + i);
                    int sl1 = sperm(k, g8 * 8 + i + 1);
                    const float* row0 = pT + sl0 * 40;
                    const float* row1 = pT + sl1 * 40;
                    float4 rA0 = *(const float4*)(row0);
                    float2 rB0 = *(const float2*)(row0 + 4);
                    float4 b00 = *(const float4*)(row0 + 8 + hb);
                    float4 b01 = *(const float4*)(row0 + 12 + hb);
                    float4 c00 = *(const float4*)(row0 + 24 + hb);
                    float4 c01 = *(const float4*)(row0 + 28 + hb);
                    float4 rA1 = *(const float4*)(row1);
                    float2 rB1 = *(const float2*)(row1 + 4);
                    float4 b10 = *(const float4*)(row1 + 8 + hb);
                    float4 b11 = *(const float4*)(row1 + 12 + hb);
                    float4 c10 = *(const float4*)(row1 + 24 + hb);
                    float4 c11 = *(const float4*)(row1 + 28 + hb);
                    float dp0 = bias, dp1 = bias;
                    dp0 = fmaf(rA0.x, w6[0], dp0); dp1 = fmaf(rA1.x, w6[0], dp1);
                    dp0 = fmaf(rA0.y, w6[1], dp0); dp1 = fmaf(rA1.y, w6[1], dp1);
                    dp0 = fmaf(rA0.z, w6[2], dp0); dp1 = fmaf(rA1.z, w6[2], dp1);
                    dp0 = fmaf(rA0.w, w6[3], dp0); dp1 = fmaf(rA1.w, w6[3], dp1);
                    dp0 = fmaf(rB0.x, w6[4], dp0); dp1 = fmaf(rB1.x, w6[4], dp1);
                    dp0 = fmaf(rB0.y, w6[5], dp0); dp1 = fmaf(rB1.y, w6[5], dp1);
                    float ex0 = __expf(dp0), ex1 = __expf(dp1);
                    float delta0 = (dp0 > 20.f) ? dp0 : __logf(1.f + ex0);
                    float delta1 = (dp1 > 20.f) ? dp1 : __logf(1.f + ex1);
                    float e10 = __builtin_amdgcn_rcpf(1.f + ex0);  // exp(-delta0)
                    float e11 = __builtin_amdgcn_rcpf(1.f + ex1);
                    float du0 = delta0 * u8[i];
                    float du1 = delta1 * u8[i + 1];
                    float e20 = e10 * e10, e40 = e20 * e20, e80 = e40 * e40;
                    float ebm0 = e80 * e10;
                    float eb0 = h ? ebm0 : e10;
                    float p0 = eb0,       p1 = eb0 * e10, p2 = eb0 * e20, p3 = p1 * e20;
                    float p4 = eb0 * e40, p5 = p1 * e40,  p6 = p2 * e40,  p7 = p3 * e40;
                    float e21 = e11 * e11, e41 = e21 * e21, e81 = e41 * e41;
                    float ebm1 = e81 * e11;
                    float eb1 = h ? ebm1 : e11;
                    float q0 = eb1,       q1 = eb1 * e11, q2 = eb1 * e21, q3 = q1 * e21;
                    float q4 = eb1 * e41, q5 = q1 * e41,  q6 = q2 * e41,  q7 = q3 * e41;
                    float ya, yb_;
                    hst[0] = fmaf(hst[0], p0, du0 * b00.x); ya  = hst[0] * c00.x;
                    hst[1] = fmaf(hst[1], p1, du0 * b00.y); yb_ = hst[1] * c00.y;
                    hst[2] = fmaf(hst[2], p2, du0 * b00.z); ya  = fmaf(hst[2], c00.z, ya);
                    hst[3] = fmaf(hst[3], p3, du0 * b00.w); yb_ = fmaf(hst[3], c00.w, yb_);
                    hst[4] = fmaf(hst[4], p4, du0 * b01.x); ya  = fmaf(hst[4], c01.x, ya);
                    hst[5] = fmaf(hst[5], p5, du0 * b01.y); yb_ = fmaf(hst[5], c01.y, yb_);
                    hst[6] = fmaf(hst[6], p6, du0 * b01.z); ya  = fmaf(hst[6], c01.z, ya);
                    hst[7] = fmaf(hst[7], p7, du0 * b01.w); yb_ = fmaf(hst[7], c01.w, yb_);
                    float yp0 = fmaf(Dd_eff, u8[i], ya + yb_);
                    float yf0 = yp0 + __shfl_xor(yp0, 1);
                    float yo0 = __shfl_xor(yf0, 2);
                    if ((t & 3) == 0) yb[sl0 * 96 + (d >> 1)] = packbf(yf0, yo0);
                    hst[0] = fmaf(hst[0], q0, du1 * b10.x); ya  = hst[0] * c10.x;
                    hst[1] = fmaf(hst[1], q1, du1 * b10.y); yb_ = hst[1] * c10.y;
                    hst[2] = fmaf(hst[2], q2, du1 * b10.z); ya  = fmaf(hst[2], c10.z, ya);
                    hst[3] = fmaf(hst[3], q3, du1 * b10.w); yb_ = fmaf(hst[3], c10.w, yb_);
                    hst[4] = fmaf(hst[4], q4, du1 * b11.x); ya  = fmaf(hst[4], c11.x, ya);
                    hst[5] = fmaf(hst[5], q5, du1 * b11.y); yb_ = fmaf(hst[5], c11.y, yb_);
                    hst[6] = fmaf(hst[6], q6, du1 * b11.z); ya  = fmaf(hst[6], c11.z, ya);
                    hst[7] = fmaf(hst[7], q7, du1 * b11.w); yb_ = fmaf(hst[7], c11.w, yb_);
                    float yp1 = fmaf(Dd_eff, u8[i + 1], ya + yb_);
                    float yf1 = yp1 + __shfl_xor(yp1, 1);
                    float yo1 = __shfl_xor(yf1, 2);
                    if ((t & 3) == 0) yb[sl1 * 96 + (d >> 1)] = packbf(yf1, yo1);
                }
            }
        } else if (__all(pw)) {
            for (int g8 = 0; g8 < 8; ++g8) {
                float u8[8];
                #pragma unroll
                for (int i = 0; i < 8; i++)
                    u8[i] = xbase[sperm(k, g8 * 8 + i) * 192 + d];
                #pragma unroll
                for (int i = 0; i < 8; i++) {
                    int sl = sperm(k, g8 * 8 + i);
                    const float* row = pT + sl * 40;
                    float4 rA = *(const float4*)(row);
                    float2 rB = *(const float2*)(row + 4);
                    float dp = bias;
                    dp = fmaf(rA.x, w6[0], dp); dp = fmaf(rA.y, w6[1], dp);
                    dp = fmaf(rA.z, w6[2], dp); dp = fmaf(rA.w, w6[3], dp);
                    dp = fmaf(rB.x, w6[4], dp); dp = fmaf(rB.y, w6[5], dp);
                    float delta = (dp > 20.f) ? dp : __logf(1.f + __expf(dp));
                    float du = delta * u8[i];
                    float e1 = __expf(delta * a0);
                    float eb = __expf(delta * c0);
                    float e2 = e1 * e1, e4 = e2 * e2;
                    float p0 = eb,      p1 = eb * e1, p2 = eb * e2, p3 = p1 * e2;
                    float p4 = p0 * e4, p5 = p1 * e4, p6 = p2 * e4, p7 = p3 * e4;
                    float4 bq0 = *(const float4*)(row + 8 + hb);
                    float4 bq1 = *(const float4*)(row + 12 + hb);
                    float4 cq0 = *(const float4*)(row + 24 + hb);
                    float4 cq1 = *(const float4*)(row + 28 + hb);
                    float y0, y1;
                    hst[0] = fmaf(hst[0], p0, du * bq0.x); y0 = hst[0] * cq0.x;
                    hst[1] = fmaf(hst[1], p1, du * bq0.y); y1 = hst[1] * cq0.y;
                    hst[2] = fmaf(hst[2], p2, du * bq0.z); y0 = fmaf(hst[2], cq0.z, y0);
                    hst[3] = fmaf(hst[3], p3, du * bq0.w); y1 = fmaf(hst[3], cq0.w, y1);
                    hst[4] = fmaf(hst[4], p4, du * bq1.x); y0 = fmaf(hst[4], cq1.x, y0);
                    hst[5] = fmaf(hst[5], p5, du * bq1.y); y1 = fmaf(hst[5], cq1.y, y1);
                    hst[6] = fmaf(hst[6], p6, du * bq1.z); y0 = fmaf(hst[6], cq1.z, y0);
                    hst[7] = fmaf(hst[7], p7, du * bq1.w); y1 = fmaf(hst[7], cq1.w, y1);
                    float yp = fmaf(Dd_eff, u8[i], y0 + y1);
                    float yfull = yp + __shfl_xor(yp, 1);
                    float yo2 = __shfl_xor(yfull, 2);
                    if ((t & 3) == 0) yb[sl * 96 + (d >> 1)] = packbf(yfull, yo2);
                }
            }
        } else {
            for (int l = 0; l < 64; l++) {
                int sl = sperm(k, l);
                float u = xbase[sl * 192 + d];
                const float* row = pT + sl * 40;
                float dp = bias;
                #pragma unroll
                for (int r = 0; r < 6; r++) dp = fmaf(row[r], w6[r], dp);
                float delta = (dp > 20.f) ? dp : __logf(1.f + __expf(dp));
                float du = delta * u;
                float yp = 0.f;
                #pragma unroll
                for (int n = 0; n < 8; n++) {
                    float e = __expf(delta * a8[n]);
                    hst[n] = fmaf(hst[n], e, du * row[8 + hb + n]);
                    yp = fmaf(hst[n], row[24 + hb + n], yp);
                }
                yp = fmaf(Dd_eff, u, yp);
                float yfull = yp + __shfl_xor(yp, 1);
                float yo2 = __shfl_xor(yfull, 2);
                if ((t & 3) == 0) yb[sl * 96 + (d >> 1)] = packbf(yfull, yo2);
            }
        }
    }
}

// ---- kEF: y = sum of 4 bf16 partials; LN(192)+silu(z) gate -> gs in LDS;
// out_proj GEMV (48 cols) + residual recompute + final blend.
// block = (chunk, cgf in {0,1}); grid 512 x 512 thr -> 16 waves/CU.
__global__ __launch_bounds__(512, 4) void kEF(
        const unsigned int* __restrict__ yk01, const unsigned int* __restrict__ yk23,
        const unsigned int* __restrict__ zg_b,
        const float* __restrict__ og, const float* __restrict__ ob,
        const float* __restrict__ Wout,        // (192,96)
        const float* __restrict__ x, const float* __restrict__ stats,
        const float* __restrict__ gamma, const float* __restrict__ beta,
        const float* __restrict__ alpha, float* __restrict__ out) {
    int blk = blockIdx.x;
    int xcd = blk & 7, j = blk >> 3;         // j: 0..63
    int chunk = xcd * 32 + (j >> 1), cgf = j & 1;
    int b = chunk >> 6, chh = (chunk >> 3) & 7, chw = chunk & 7;
    __shared__ float gs[64 * 193];
    int t = threadIdx.x;
    // LN + gate for all 64 positions, 8 lanes per position, one pass
    {
        int p = t >> 3, o = t & 7;
        int par = o & 1;
        size_t rb = (size_t)chunk * 6144 + p * 96;
        const unsigned int* r0 = yk01 + rb;
        const unsigned int* r1 = yk01 + 1572864 + rb;
        const unsigned int* r2 = yk23 + rb;
        const unsigned int* r3 = yk23 + 1572864 + rb;
        float ys[24];
        float s = 0.f, sq = 0.f;
        #pragma unroll
        for (int jj = 0; jj < 24; jj++) {
            int i = o + 8 * jj;
            int wi = i >> 1;
            int sh = par ? 16 : 0;
            float v = bf2f((r0[wi] >> sh) & 0xFFFFu) + bf2f((r1[wi] >> sh) & 0xFFFFu)
                    + bf2f((r2[wi] >> sh) & 0xFFFFu) + bf2f((r3[wi] >> sh) & 0xFFFFu);
            ys[jj] = v; s += v; sq += v * v;
        }
        s += __shfl_xor(s, 1); sq += __shfl_xor(sq, 1);
        s += __shfl_xor(s, 2); sq += __shfl_xor(sq, 2);
        s += __shfl_xor(s, 4); sq += __shfl_xor(sq, 4);
        float m = s * (1.f / 192.f);
        float rinv = rsqrtf(sq * (1.f / 192.f) - m * m + 1e-5f);
        const unsigned int* z = zg_b + (size_t)chunk * 6144;
        #pragma unroll
        for (int jj = 0; jj < 24; jj++) {
            int i = o + 8 * jj;
            float ln = (ys[jj] - m) * rinv * og[i] + ob[i];
            unsigned int zw = z[(i >> 1) * 64 + p];
            float zv = bf2f(par ? (zw >> 16) : (zw & 0xFFFFu));
            gs[p * 193 + i] = ln * siluf_(zv);
        }
    }
    __syncthreads();
    // out_proj GEMV: cols [cgf*48 + wv*6, +6), u from LDS (conflict-free)
    {
        int p = t & 63;
        int wv = __builtin_amdgcn_readfirstlane(t >> 6);   // 0..7
        int cbase = cgf * 48 + wv * 6;
        float acc[6];
        #pragma unroll
        for (int i = 0; i < 6; i++) acc[i] = 0.f;
        for (int dd = 0; dd < 192; dd++) {
            float u = gs[p * 193 + dd];
            const float* w = Wout + dd * 96 + cbase;       // uniform -> s_load
            #pragma unroll
            for (int i = 0; i < 6; i++) acc[i] = fmaf(u, w[i], acc[i]);
        }
        float al = alpha[0];
        int hh = chh * 8 + (p >> 3), ww = chw * 8 + (p & 7);
        #pragma unroll
        for (int i = 0; i < 6; i++) {
            int c = cbase + i;
            int bc = b * 96 + c;
            size_t gi = (((size_t)bc) * 64 + hh) * 64 + ww;
            float xv = x[gi];
            float xn = (xv - stats[bc]) * stats[384 + bc] * gamma[c] + beta[c];
            out[gi] = xv + al * (siluf_(xn) + acc[i]);
        }
    }
}

extern "C" void kernel_launch(void* const* d_in, const int* in_sizes, int n_in,
                              void* d_out, int out_size, void* d_ws, size_t ws_size,
                              hipStream_t stream) {
    const float* x        = (const float*)d_in[0];
    const float* gamma    = (const float*)d_in[1];
    const float* beta     = (const float*)d_in[2];
    const float* alpha    = (const float*)d_in[3];
    const float* ln1_g    = (const float*)d_in[4];
    const float* ln1_b    = (const float*)d_in[5];
    const float* in_proj  = (const float*)d_in[6];
    const float* conv_w   = (const float*)d_in[7];
    const float* conv_b   = (const float*)d_in[8];
    const float* x_proj   = (const float*)d_in[9];
    const float* dt_w     = (const float*)d_in[10];
    const float* dt_b     = (const float*)d_in[11];
    const float* A_logs   = (const float*)d_in[12];
    const float* Ds       = (const float*)d_in[13];
    const float* onorm_g  = (const float*)d_in[14];
    const float* onorm_b  = (const float*)d_in[15];
    const float* out_proj = (const float*)d_in[16];
    float* out = (float*)d_out;

    float* ws    = (float*)d_ws;
    float* stats = ws;                            // 768 f
    float* x0T   = ws + 768;                      // 3,145,728 f
    unsigned int* zg_b = (unsigned int*)(x0T + 3145728);   // 1,572,864 u32
    unsigned int* yk01 = zg_b + 1572864;          // 3,145,728 u32
    unsigned int* yk23 = yk01 + 3145728;          // 3,145,728 u32 (total 44.04 MB, proven)

    hipLaunchKernelGGL(k1a_stats, dim3(384), dim3(256), 0, stream, x, stats);
    hipLaunchKernelGGL(kAB, dim3(512), dim3(512), 0, stream,
                       x, stats, gamma, beta, ln1_g, ln1_b, in_proj,
                       conv_w, conv_b, x0T, zg_b);
    hipLaunchKernelGGL(kD, dim3(1024), dim3(384), 0, stream,
                       x0T, x_proj, dt_w, dt_b, A_logs, Ds, yk01, yk23);
    hipLaunchKernelGGL(kEF, dim3(512), dim3(512), 0, stream,
                       yk01, yk23, zg_b, onorm_g, onorm_b, out_proj,
                       x, stats, gamma, beta, alpha, out);
}